// Round 1
// baseline (157.772 us; speedup 1.0000x reference)
//
#include <hip/hip_runtime.h>

#define BTOT 8192
#define TT 512

__device__ __forceinline__ float sigm(float x) {
    return 1.0f / (1.0f + __expf(-x));
}
__device__ __forceinline__ float tanh_f(float x) {
    // 1 - 2/(1+e^{2x}): exact limits at +-inf, no overflow issues
    return 1.0f - 2.0f / (1.0f + __expf(2.0f * x));
}

__global__ __launch_bounds__(64) void lstm_kernel(
    const float* __restrict__ x,
    const float* __restrict__ W_ih,
    const float* __restrict__ W_hh,
    const float* __restrict__ b_ih,
    const float* __restrict__ b_hh,
    const float* __restrict__ fc1_w,
    const float* __restrict__ fc1_b,
    const float* __restrict__ fc2_w,
    const float* __restrict__ fc2_b,
    float* __restrict__ out)
{
    const int lane = threadIdx.x;            // block = 1 wave of 64
    const int jj = lane % 5;                 // hidden unit owned
    const bool active = (lane < 60);         // 12 groups of 5; lanes 60-63 idle
    const int base = active ? (lane - jj) : 55;  // group base lane (idlers alias group 11, read-only)
    const int group = base / 5;
    const int b_raw = blockIdx.x * 12 + group;
    const bool valid = active && (b_raw < BTOT);
    const int b = (b_raw < BTOT) ? b_raw : (BTOT - 1);

    // Per-lane weights: rows jj, jj+5, jj+10, jj+15 of W_ih / W_hh (gate order i,f,g,o)
    float wih[4][5], whh[4][5], bias[4];
    #pragma unroll
    for (int g = 0; g < 4; ++g) {
        const int row = jj + 5 * g;
        #pragma unroll
        for (int i = 0; i < 5; ++i) {
            wih[g][i] = W_ih[row * 5 + i];
            whh[g][i] = W_hh[row * 5 + i];
        }
        bias[g] = b_ih[row] + b_hh[row];
    }

    const float* xb = x + (size_t)b * (TT * 5);

    float h = 0.0f, c = 0.0f;

    for (int t0 = 0; t0 < TT; t0 += 4) {
        // 4 timesteps = 20 floats = 5 aligned float4 loads (per-thread contiguous stream)
        const float4 v0 = *(const float4*)(xb + t0 * 5);
        const float4 v1 = *(const float4*)(xb + t0 * 5 + 4);
        const float4 v2 = *(const float4*)(xb + t0 * 5 + 8);
        const float4 v3 = *(const float4*)(xb + t0 * 5 + 12);
        const float4 v4 = *(const float4*)(xb + t0 * 5 + 16);
        float xs[20];
        xs[0]=v0.x;  xs[1]=v0.y;  xs[2]=v0.z;  xs[3]=v0.w;
        xs[4]=v1.x;  xs[5]=v1.y;  xs[6]=v1.z;  xs[7]=v1.w;
        xs[8]=v2.x;  xs[9]=v2.y;  xs[10]=v2.z; xs[11]=v2.w;
        xs[12]=v3.x; xs[13]=v3.y; xs[14]=v3.z; xs[15]=v3.w;
        xs[16]=v4.x; xs[17]=v4.y; xs[18]=v4.z; xs[19]=v4.w;

        #pragma unroll
        for (int s = 0; s < 4; ++s) {
            // assemble full h vector from the 5 lanes of this group
            float hv[5];
            #pragma unroll
            for (int k = 0; k < 5; ++k)
                hv[k] = __shfl(h, base + k, 64);

            float acc0 = bias[0], acc1 = bias[1], acc2 = bias[2], acc3 = bias[3];
            #pragma unroll
            for (int i = 0; i < 5; ++i) {
                const float xv = xs[s * 5 + i];
                acc0 = fmaf(wih[0][i], xv, acc0);
                acc1 = fmaf(wih[1][i], xv, acc1);
                acc2 = fmaf(wih[2][i], xv, acc2);
                acc3 = fmaf(wih[3][i], xv, acc3);
            }
            #pragma unroll
            for (int k = 0; k < 5; ++k) {
                const float hk = hv[k];
                acc0 = fmaf(whh[0][k], hk, acc0);
                acc1 = fmaf(whh[1][k], hk, acc1);
                acc2 = fmaf(whh[2][k], hk, acc2);
                acc3 = fmaf(whh[3][k], hk, acc3);
            }
            const float ig = sigm(acc0);
            const float fg = sigm(acc1);
            const float gg = tanh_f(acc2);
            const float og = sigm(acc3);
            c = fmaf(fg, c, ig * gg);
            h = og * tanh_f(c);
        }
    }

    // gather final h, lane 0 of each group computes both FC heads
    float hv[5];
    #pragma unroll
    for (int k = 0; k < 5; ++k)
        hv[k] = __shfl(h, base + k, 64);

    if (valid && jj == 0) {
        float p = fc1_b[0];
        float v = fc2_b[0];
        #pragma unroll
        for (int k = 0; k < 5; ++k) {
            p = fmaf(fc1_w[k], hv[k], p);
            v = fmaf(fc2_w[k], hv[k], v);
        }
        out[b] = p;           // price
        out[BTOT + b] = v;    // volume
    }
}

extern "C" void kernel_launch(void* const* d_in, const int* in_sizes, int n_in,
                              void* d_out, int out_size, void* d_ws, size_t ws_size,
                              hipStream_t stream) {
    const float* x     = (const float*)d_in[0];
    const float* W_ih  = (const float*)d_in[1];
    const float* W_hh  = (const float*)d_in[2];
    const float* b_ih  = (const float*)d_in[3];
    const float* b_hh  = (const float*)d_in[4];
    const float* fc1_w = (const float*)d_in[5];
    const float* fc1_b = (const float*)d_in[6];
    const float* fc2_w = (const float*)d_in[7];
    const float* fc2_b = (const float*)d_in[8];
    float* out = (float*)d_out;

    const int blocks = (BTOT + 11) / 12;  // 683 one-wave blocks
    lstm_kernel<<<blocks, 64, 0, stream>>>(x, W_ih, W_hh, b_ih, b_hh,
                                           fc1_w, fc1_b, fc2_w, fc2_b, out);
}